// Round 3
// baseline (59.567 us; speedup 1.0000x reference)
//
#include <hip/hip_runtime.h>

// PolyAttn collapse: a = s^4/|s^4| == 1.0 identically, so
//   out[b,n,:] = vsum[b,:] @ w_o  (independent of n, q, k, alpha),
//   vsum[b,:]  = (sum_n x[b,n,:]) @ w_qkv[:, 2H:3H].
// Single persistent kernel (256 blocks = 1/CU, co-resident) with manual
// grid barriers; tiny init kernel zeroes accumulators+counters each call.

#define B_ 4
#define N_ 2048
#define D_ 1024
#define H_ 1024
#define H3_ 3072
#define NB_ 256
#define NT_ 512

// ws layout (floats): xsum[B*D] | vsum[B*H] | orow[B*D] | ctrl[192 ints]
// barrier i: cnt = ctrl[i*64], gen = ctrl[i*64 + 32]   (separate cachelines)

__global__ void k_init(float4* __restrict__ z4, int* __restrict__ ctrl) {
    const int i = blockIdx.x * 256 + threadIdx.x;    // 0..3071 float4s = 12288 floats
    z4[i] = make_float4(0.f, 0.f, 0.f, 0.f);
    if (blockIdx.x == 0 && threadIdx.x < 192) ctrl[threadIdx.x] = 0;
}

__device__ __forceinline__ void gbar(int* __restrict__ ctrl, int idx) {
    __syncthreads();                                 // drains all vmem incl. atomics
    if (threadIdx.x == 0) {
        int* cnt = ctrl + idx * 64;
        int* gen = cnt + 32;
        __threadfence();
        int old = __hip_atomic_fetch_add(cnt, 1, __ATOMIC_RELAXED,
                                         __HIP_MEMORY_SCOPE_AGENT);
        if (old == NB_ - 1) {
            __hip_atomic_store(gen, 1, __ATOMIC_RELEASE, __HIP_MEMORY_SCOPE_AGENT);
        } else {
            while (__hip_atomic_load(gen, __ATOMIC_RELAXED,
                                     __HIP_MEMORY_SCOPE_AGENT) == 0)
                __builtin_amdgcn_s_sleep(2);
        }
        __threadfence();
    }
    __syncthreads();
}

__device__ __forceinline__ float agent_ld(const float* p) {
    return __hip_atomic_load(p, __ATOMIC_RELAXED, __HIP_MEMORY_SCOPE_AGENT);
}

__global__ __launch_bounds__(NT_, 1) void k_fused(
        const float* __restrict__ x, const float* __restrict__ w_qkv,
        const float* __restrict__ w_o, float* __restrict__ out,
        float* __restrict__ xsum, float* __restrict__ vsum,
        float* __restrict__ orow, int* __restrict__ ctrl) {
    const int blk = blockIdx.x;
    const int tid = threadIdx.x;
    __shared__ float s_in[64];

    // ---- phase 1: xsum[b,d] += sum over this block's 32 rows of x ----------
    {
        const int b    = blk >> 6;        // 0..3
        const int g    = blk & 63;        // row group: rows g*32 .. +31
        const int half = tid >> 8;        // 0/1 -> 16 rows each
        const int c    = tid & 255;       // float4 column
        const float4* x4 = reinterpret_cast<const float4*>(x);
        size_t base = ((size_t)b * N_ + g * 32 + half * 16) * (D_ / 4) + c;
        float4 acc = make_float4(0.f, 0.f, 0.f, 0.f);
#pragma unroll 8
        for (int i = 0; i < 16; ++i) {
            float4 v = x4[base + (size_t)i * (D_ / 4)];
            acc.x += v.x; acc.y += v.y; acc.z += v.z; acc.w += v.w;
        }
        float* dst = xsum + b * D_ + c * 4;
        atomicAdd(dst + 0, acc.x);
        atomicAdd(dst + 1, acc.y);
        atomicAdd(dst + 2, acc.z);
        atomicAdd(dst + 3, acc.w);
    }
    gbar(ctrl, 0);

    // ---- phase 2: vsum[b,h] += sum_{d in 16-chunk} xsum[b,d]*Wv[d,h] -------
    {
        const int hx = blk & 3;           // h group (256 wide)
        const int d0 = (blk >> 2) * 16;   // 64 chunks of 16 d
        if (tid < 64)
            s_in[tid] = agent_ld(&xsum[(tid >> 4) * D_ + d0 + (tid & 15)]);
        __syncthreads();
        if (tid < 256) {
            const int h = hx * 256 + tid;
            float a0 = 0.f, a1 = 0.f, a2 = 0.f, a3 = 0.f;
#pragma unroll
            for (int i = 0; i < 16; ++i) {
                const float w = w_qkv[(size_t)(d0 + i) * H3_ + 2 * H_ + h];
                a0 += s_in[ 0 + i] * w;
                a1 += s_in[16 + i] * w;
                a2 += s_in[32 + i] * w;
                a3 += s_in[48 + i] * w;
            }
            atomicAdd(&vsum[0 * H_ + h], a0);
            atomicAdd(&vsum[1 * H_ + h], a1);
            atomicAdd(&vsum[2 * H_ + h], a2);
            atomicAdd(&vsum[3 * H_ + h], a3);
        }
    }
    gbar(ctrl, 1);

    // ---- phase 3: orow[b,d] += sum_{h in 16-chunk} vsum[b,h]*Wo[h,d] -------
    {
        const int dx = blk & 3;
        const int h0 = (blk >> 2) * 16;
        if (tid < 64)
            s_in[tid] = agent_ld(&vsum[(tid >> 4) * H_ + h0 + (tid & 15)]);
        __syncthreads();
        if (tid < 256) {
            const int d = dx * 256 + tid;
            float a0 = 0.f, a1 = 0.f, a2 = 0.f, a3 = 0.f;
#pragma unroll
            for (int i = 0; i < 16; ++i) {
                const float w = w_o[(size_t)(h0 + i) * D_ + d];
                a0 += s_in[ 0 + i] * w;
                a1 += s_in[16 + i] * w;
                a2 += s_in[32 + i] * w;
                a3 += s_in[48 + i] * w;
            }
            atomicAdd(&orow[0 * D_ + d], a0);
            atomicAdd(&orow[1 * D_ + d], a1);
            atomicAdd(&orow[2 * D_ + d], a2);
            atomicAdd(&orow[3 * D_ + d], a3);
        }
    }
    gbar(ctrl, 2);

    // ---- phase 4: out[b, rows, :] = orow[b, :] broadcast -------------------
    {
        const int b    = blk >> 6;
        const int row0 = (blk & 63) * 32;   // rows within batch (never straddles b)
        const int half = tid >> 8;
        const int c    = tid & 255;
        float4 val;
        val.x = agent_ld(&orow[b * D_ + c * 4 + 0]);
        val.y = agent_ld(&orow[b * D_ + c * 4 + 1]);
        val.z = agent_ld(&orow[b * D_ + c * 4 + 2]);
        val.w = agent_ld(&orow[b * D_ + c * 4 + 3]);
        float4* out4 = reinterpret_cast<float4*>(out);
        size_t base = ((size_t)b * N_ + row0 + half * 16) * (D_ / 4) + c;
#pragma unroll 8
        for (int i = 0; i < 16; ++i)
            out4[base + (size_t)i * (D_ / 4)] = val;
    }
}

extern "C" void kernel_launch(void* const* d_in, const int* in_sizes, int n_in,
                              void* d_out, int out_size, void* d_ws, size_t ws_size,
                              hipStream_t stream) {
    const float* x     = (const float*)d_in[0];   // [B, N, D]
    const float* w_qkv = (const float*)d_in[1];   // [D, 3H]
    const float* w_o   = (const float*)d_in[2];   // [H, D]
    // d_in[3] = alpha — provably unused (a == 1 regardless of alpha).
    float* out = (float*)d_out;                   // [B, N, D] fp32

    float* xsum = (float*)d_ws;                   // 4096 floats
    float* vsum = xsum + B_ * D_;                 // 4096 floats
    float* orow = vsum + B_ * H_;                 // 4096 floats
    int*   ctrl = (int*)(orow + B_ * D_);         // 192 ints

    k_init<<<12, 256, 0, stream>>>((float4*)d_ws, ctrl);
    k_fused<<<NB_, NT_, 0, stream>>>(x, w_qkv, w_o, out, xsum, vsum, orow, ctrl);
}

// Round 4
// 55.676 us; speedup vs baseline: 1.0699x; 1.0699x over previous
//
#include <hip/hip_runtime.h>

// PolyAttn collapse: a = s^4/|s^4| == 1.0 identically, so
//   out[b,n,:] = vsum[b,:] @ w_o  (independent of n, q, k, alpha),
//   vsum[b,:]  = (sum_n x[b,n,:]) @ w_qkv[:, 2H:3H].
// 2-node graph: tiny init + one persistent kernel with TWO cheap grid
// barriers (per-block release flags, s_sleep backoff). vsum+orow fused:
// 64 blocks each own a 16-wide h-chunk (removes one barrier vs R3).

#define B_ 4
#define N_ 2048
#define D_ 1024
#define H_ 1024
#define H3_ 3072
#define NB_ 256
#define NT_ 512

// ws layout: xsum[4096]f | orow[4096]f | ctrl[2112]i
//   ctrl: cnt0=ctrl[0], cnt1=ctrl[32], flags0=ctrl+64 (256 x stride 4),
//         flags1=ctrl+1088 (256 x stride 4)

__global__ void k_init(float4* __restrict__ z4) {
    const int i = blockIdx.x * 256 + threadIdx.x;   // 12 x 256 = 3072 float4s
    if (i < 2576 + 16) z4[i] = make_float4(0.f, 0.f, 0.f, 0.f);  // 10368 floats
}

__device__ __forceinline__ float agent_ld(const float* p) {
    return __hip_atomic_load(p, __ATOMIC_RELAXED, __HIP_MEMORY_SCOPE_AGENT);
}

// Cheap grid barrier: arrive on cnt; last block broadcast-releases by
// writing one flag per block (distinct 16B offsets); waiters poll own flag.
__device__ __forceinline__ void gbar(int* __restrict__ cnt, int* __restrict__ flags) {
    __shared__ int s_last;
    __syncthreads();                       // drains vmcnt (atomics ordered)
    if (threadIdx.x == 0) {
        __threadfence();
        const int old = __hip_atomic_fetch_add(cnt, 1, __ATOMIC_ACQ_REL,
                                               __HIP_MEMORY_SCOPE_AGENT);
        s_last = (old == NB_ - 1);
    }
    __syncthreads();
    if (s_last) {
        if (threadIdx.x < NB_)
            __hip_atomic_store(flags + threadIdx.x * 4, 1, __ATOMIC_RELAXED,
                               __HIP_MEMORY_SCOPE_AGENT);
    } else if (threadIdx.x == 0) {
        while (__hip_atomic_load(flags + blockIdx.x * 4, __ATOMIC_RELAXED,
                                 __HIP_MEMORY_SCOPE_AGENT) == 0)
            __builtin_amdgcn_s_sleep(8);
        __threadfence();
    }
    __syncthreads();
}

__global__ __launch_bounds__(NT_, 1) void k_fused(
        const float* __restrict__ x, const float* __restrict__ w_qkv,
        const float* __restrict__ w_o, float* __restrict__ out,
        float* __restrict__ xsum, float* __restrict__ orow,
        int* __restrict__ ctrl) {
    const int blk = blockIdx.x;
    const int tid = threadIdx.x;
    __shared__ float4 s4[256];                 // phase1 combine / phase3 bcast
    __shared__ float  s_xs[4 * D_];            // 16 KB, phase 2
    __shared__ float  s_red[4 * NT_];          // 8 KB,  phase 2
    __shared__ float  s_vs[4 * 16];            // phase 2

    // ---- phase 1: xsum[b,d] += sum over this block's 32 rows of x ----------
    {
        const int b    = blk >> 6;             // 0..3
        const int g    = blk & 63;             // 32-row group
        const int half = tid >> 8;             // 0/1 -> 16 rows each
        const int c    = tid & 255;            // float4 column
        const float4* x4 = reinterpret_cast<const float4*>(x);
        size_t base = ((size_t)b * N_ + g * 32 + half * 16) * (D_ / 4) + c;
        float4 acc = make_float4(0.f, 0.f, 0.f, 0.f);
#pragma unroll 16
        for (int i = 0; i < 16; ++i) {
            float4 v = x4[base + (size_t)i * (D_ / 4)];
            acc.x += v.x; acc.y += v.y; acc.z += v.z; acc.w += v.w;
        }
        if (half == 0) s4[c] = acc;
        __syncthreads();
        if (half == 1) {
            float4 o = s4[c];
            acc.x += o.x; acc.y += o.y; acc.z += o.z; acc.w += o.w;
            float* dst = xsum + b * D_ + c * 4;
            atomicAdd(dst + 0, acc.x);
            atomicAdd(dst + 1, acc.y);
            atomicAdd(dst + 2, acc.z);
            atomicAdd(dst + 3, acc.w);
        }
    }
    gbar(ctrl + 0, ctrl + 64);

    // ---- phase 2 (64 blocks): vs[b,hc]=xsum@Wv[:,hc]; orow+=vs@Wo[hc,:] ----
    if (blk < 64) {
        const int h0 = blk * 16;
        for (int i = tid; i < 4 * D_; i += NT_) s_xs[i] = agent_ld(xsum + i);
        __syncthreads();
        {   // 512 thr = 32 d-groups x 16 h
            const int h  = tid & 15;
            const int dg = tid >> 4;
            const float* wv = w_qkv + 2 * H_ + h0 + h;
            float a0 = 0.f, a1 = 0.f, a2 = 0.f, a3 = 0.f;
#pragma unroll 4
            for (int i = 0; i < 32; ++i) {
                const int d = dg * 32 + i;
                const float w = wv[(size_t)d * H3_];
                a0 += s_xs[0 * D_ + d] * w;
                a1 += s_xs[1 * D_ + d] * w;
                a2 += s_xs[2 * D_ + d] * w;
                a3 += s_xs[3 * D_ + d] * w;
            }
            s_red[0 * NT_ + tid] = a0;   // layout [b][dg][h] = b*512 + tid
            s_red[1 * NT_ + tid] = a1;
            s_red[2 * NT_ + tid] = a2;
            s_red[3 * NT_ + tid] = a3;
        }
        __syncthreads();
        if (tid < 64) {
            const int b = tid >> 4, hh = tid & 15;
            float v = 0.f;
#pragma unroll
            for (int dg = 0; dg < 32; ++dg) v += s_red[b * NT_ + dg * 16 + hh];
            s_vs[b * 16 + hh] = v;
        }
        __syncthreads();
#pragma unroll
        for (int k = 0; k < 2; ++k) {
            const int d = tid + k * NT_;
            float o0 = 0.f, o1 = 0.f, o2 = 0.f, o3 = 0.f;
#pragma unroll
            for (int j = 0; j < 16; ++j) {
                const float w = w_o[(size_t)(h0 + j) * D_ + d];
                o0 += s_vs[0 * 16 + j] * w;
                o1 += s_vs[1 * 16 + j] * w;
                o2 += s_vs[2 * 16 + j] * w;
                o3 += s_vs[3 * 16 + j] * w;
            }
            atomicAdd(&orow[0 * D_ + d], o0);
            atomicAdd(&orow[1 * D_ + d], o1);
            atomicAdd(&orow[2 * D_ + d], o2);
            atomicAdd(&orow[3 * D_ + d], o3);
        }
    }
    gbar(ctrl + 32, ctrl + 1088);

    // ---- phase 3: out[b, rows, :] = orow[b, :] broadcast -------------------
    {
        const int b    = blk >> 6;
        const int g    = blk & 63;
        const int half = tid >> 8;
        const int c    = tid & 255;
        if (half == 0) {
            float4 v;
            v.x = agent_ld(orow + b * D_ + c * 4 + 0);
            v.y = agent_ld(orow + b * D_ + c * 4 + 1);
            v.z = agent_ld(orow + b * D_ + c * 4 + 2);
            v.w = agent_ld(orow + b * D_ + c * 4 + 3);
            s4[c] = v;
        }
        __syncthreads();
        const float4 val = s4[c];
        float4* out4 = reinterpret_cast<float4*>(out);
        size_t base = ((size_t)b * N_ + g * 32 + half * 16) * (D_ / 4) + c;
#pragma unroll 16
        for (int i = 0; i < 16; ++i)
            out4[base + (size_t)i * (D_ / 4)] = val;
    }
}

extern "C" void kernel_launch(void* const* d_in, const int* in_sizes, int n_in,
                              void* d_out, int out_size, void* d_ws, size_t ws_size,
                              hipStream_t stream) {
    const float* x     = (const float*)d_in[0];   // [B, N, D]
    const float* w_qkv = (const float*)d_in[1];   // [D, 3H]
    const float* w_o   = (const float*)d_in[2];   // [H, D]
    // d_in[3] = alpha — provably unused (a == 1 regardless of alpha).
    float* out = (float*)d_out;                   // [B, N, D] fp32

    float* xsum = (float*)d_ws;                   // 4096 floats
    float* orow = xsum + B_ * D_;                 // 4096 floats
    int*   ctrl = (int*)(orow + B_ * D_);         // 2112 ints

    k_init<<<12, 256, 0, stream>>>((float4*)d_ws);
    k_fused<<<NB_, NT_, 0, stream>>>(x, w_qkv, w_o, out, xsum, orow, ctrl);
}

// Round 5
// 35.792 us; speedup vs baseline: 1.6642x; 1.5555x over previous
//
#include <hip/hip_runtime.h>

// PolyAttn collapse: a = s^4/|s^4| == 1.0 identically, so
//   out[b,n,:] = vsum[b,:] @ w_o  (independent of n, q, k, alpha),
//   vsum[b,:]  = (sum_n x[b,n,:]) @ w_qkv[:, 2H:3H].
// Grid barriers measured ~20us each on this part (R3/R4) -> abandoned.
// 3-node graph instead: kA partials (+zero orow), kB reduce+vsum+orow,
// kC broadcast. Cross-kernel visibility via dispatch-boundary L2 flush.

#define B_ 4
#define N_ 2048
#define D_ 1024
#define H_ 1024
#define H3_ 3072

// ws layout (floats): part[4][64][1024] (1 MB) | orow[4][1024]
// s_xs padded: index d -> d + (d>>5) to break the dg-stride-32 bank conflict.
#define XS(b, d) s_xs[(b) * 1060 + (d) + ((d) >> 5)]

// ---- kA: blocks 0..255: part[b][g][:] = sum of 32 rows of x; 256..259: zero orow
__global__ __launch_bounds__(256) void kA(const float* __restrict__ x,
                                          float4* __restrict__ part4,
                                          float4* __restrict__ orow4) {
    const int blk = blockIdx.x;
    const int t   = threadIdx.x;           // 0..255 float4 column
    if (blk < 256) {
        const int b = blk >> 6, g = blk & 63;
        const float4* x4 = reinterpret_cast<const float4*>(x);
        size_t base = ((size_t)b * N_ + g * 32) * (D_ / 4) + t;
        float4 acc = make_float4(0.f, 0.f, 0.f, 0.f);
#pragma unroll 8
        for (int i = 0; i < 32; ++i) {
            float4 v = x4[base + (size_t)i * (D_ / 4)];
            acc.x += v.x; acc.y += v.y; acc.z += v.z; acc.w += v.w;
        }
        part4[((size_t)b * 64 + g) * 256 + t] = acc;
    } else {
        orow4[(blk - 256) * 256 + t] = make_float4(0.f, 0.f, 0.f, 0.f);
    }
}

// ---- kB: 64 blocks x 512 thr; block owns h-chunk [h0, h0+16).
// step1 reduce part->s_xs; step2 vsum chunk; step3 orow += vs @ Wo[chunk,:].
__global__ __launch_bounds__(512) void kB(const float4* __restrict__ part4,
                                          const float* __restrict__ w_qkv,
                                          const float* __restrict__ w_o,
                                          float* __restrict__ orow) {
    const int tid = threadIdx.x;
    const int h0  = blockIdx.x * 16;
    __shared__ float s_xs[4 * 1060 + 4];   // padded xsum, ~17 KB
    __shared__ float s_red[4 * 512];       // 8 KB
    __shared__ float s_vs[64];

    // step 1: s_xs[b][d] = sum_g part[b][g][d]   (1 MB, L2/L3-served)
#pragma unroll
    for (int k = 0; k < 2; ++k) {
        const int c  = tid + k * 512;      // 0..1023 = (b, d4)
        const int b  = c >> 8, d4 = c & 255;
        const float4* p = part4 + (size_t)b * 64 * 256 + d4;
        float4 acc = make_float4(0.f, 0.f, 0.f, 0.f);
#pragma unroll 8
        for (int g = 0; g < 64; ++g) {
            float4 v = p[(size_t)g * 256];
            acc.x += v.x; acc.y += v.y; acc.z += v.z; acc.w += v.w;
        }
        XS(b, d4 * 4 + 0) = acc.x;
        XS(b, d4 * 4 + 1) = acc.y;
        XS(b, d4 * 4 + 2) = acc.z;
        XS(b, d4 * 4 + 3) = acc.w;
    }
    __syncthreads();

    // step 2: vs[b][h] = sum_d s_xs[b][d] * Wv[d, h0+h];  512 = 32 dg x 16 h
    {
        const int h  = tid & 15;
        const int dg = tid >> 4;
        const float* wv = w_qkv + 2 * H_ + h0 + h;
        float a0 = 0.f, a1 = 0.f, a2 = 0.f, a3 = 0.f;
#pragma unroll 4
        for (int i = 0; i < 32; ++i) {
            const int d = dg * 32 + i;
            const float w = wv[(size_t)d * H3_];
            a0 += XS(0, d) * w;
            a1 += XS(1, d) * w;
            a2 += XS(2, d) * w;
            a3 += XS(3, d) * w;
        }
        s_red[0 * 512 + tid] = a0;
        s_red[1 * 512 + tid] = a1;
        s_red[2 * 512 + tid] = a2;
        s_red[3 * 512 + tid] = a3;
    }
    __syncthreads();
    if (tid < 64) {
        const int b = tid >> 4, hh = tid & 15;
        float v = 0.f;
#pragma unroll
        for (int dg = 0; dg < 32; ++dg) v += s_red[b * 512 + dg * 16 + hh];
        s_vs[b * 16 + hh] = v;
    }
    __syncthreads();

    // step 3: orow[b][d] += sum_j vs[b][j] * Wo[h0+j][d]
#pragma unroll
    for (int k = 0; k < 2; ++k) {
        const int d = tid + k * 512;
        float o0 = 0.f, o1 = 0.f, o2 = 0.f, o3 = 0.f;
#pragma unroll
        for (int j = 0; j < 16; ++j) {
            const float w = w_o[(size_t)(h0 + j) * D_ + d];
            o0 += s_vs[ 0 + j] * w;
            o1 += s_vs[16 + j] * w;
            o2 += s_vs[32 + j] * w;
            o3 += s_vs[48 + j] * w;
        }
        atomicAdd(&orow[0 * D_ + d], o0);
        atomicAdd(&orow[1 * D_ + d], o1);
        atomicAdd(&orow[2 * D_ + d], o2);
        atomicAdd(&orow[3 * D_ + d], o3);
    }
}

// ---- kC: out[b, 32 rows, :] = orow[b, :] ------------------------------------
__global__ __launch_bounds__(256) void kC(const float* __restrict__ orow,
                                          float* __restrict__ out) {
    const int blk = blockIdx.x;
    const int b = blk >> 6, g = blk & 63;
    const int t = threadIdx.x;
    const float4 val = reinterpret_cast<const float4*>(orow)[b * 256 + t];
    float4* out4 = reinterpret_cast<float4*>(out);
    size_t base = ((size_t)b * N_ + g * 32) * (D_ / 4) + t;
#pragma unroll 8
    for (int i = 0; i < 32; ++i)
        out4[base + (size_t)i * (D_ / 4)] = val;
}

extern "C" void kernel_launch(void* const* d_in, const int* in_sizes, int n_in,
                              void* d_out, int out_size, void* d_ws, size_t ws_size,
                              hipStream_t stream) {
    const float* x     = (const float*)d_in[0];   // [B, N, D]
    const float* w_qkv = (const float*)d_in[1];   // [D, 3H]
    const float* w_o   = (const float*)d_in[2];   // [H, D]
    // d_in[3] = alpha — provably unused (a == 1 regardless of alpha).
    float* out = (float*)d_out;                   // [B, N, D] fp32

    float* part = (float*)d_ws;                   // 262144 floats (1 MB)
    float* orow = part + (size_t)B_ * 64 * D_;    // 4096 floats

    kA<<<260, 256, 0, stream>>>(x, (float4*)part, (float4*)orow);
    kB<<<64, 512, 0, stream>>>((const float4*)part, w_qkv, w_o, orow);
    kC<<<256, 256, 0, stream>>>(orow, out);
}

// Round 6
// 29.451 us; speedup vs baseline: 2.0226x; 1.2153x over previous
//
#include <hip/hip_runtime.h>

// PolyAttn collapse: a = s^4/|s^4| == 1.0 identically, so
//   out[b,n,:] = vsum[b,:] @ w_o  (independent of n, q, k, alpha),
//   vsum[b,:]  = (sum_n x[b,n,:]) @ w_qkv[:, 2H:3H].
// 3-node graph (grid barriers cost ~13-20us each on 8-XCD MI355X -> banned).
// R6: narrow partials [4][8][1024] (128KB) so kB's redundant reduce is 16MB
// not 64MB; kB=128 blocks for weight-read concurrency; kA/kC 512 blocks.

#define B_ 4
#define N_ 2048
#define D_ 1024
#define H_ 1024
#define H3_ 3072

// padded LDS xsum: d -> d + (d>>4)  (stride-17 groups, kills the dg-stride-16
// bank conflict in kB step2). Per-b stride 1088 floats.
#define XS(b, d) s_xs[(b) * 1088 + (d) + ((d) >> 4)]

// ---- kA: 512 work blocks (b, ng, dq) + 4 blocks zeroing orow ---------------
// block reads x[b, ng*256 .. +256, dq*64 .. +64] and writes one partial slice.
__global__ __launch_bounds__(256) void kA(const float* __restrict__ x,
                                          float4* __restrict__ part4,
                                          float4* __restrict__ orow4) {
    const int blk = blockIdx.x;
    const int t   = threadIdx.x;
    __shared__ float4 s4[16][16];
    if (blk < 512) {
        const int b  = blk >> 7;
        const int ng = (blk >> 4) & 7;
        const int dq = blk & 15;
        const int d4 = t & 15;          // float4 lane within the 64-float slice
        const int rr = t >> 4;          // 16 row streams x 16 rows
        const float4* x4 = reinterpret_cast<const float4*>(x);
        size_t base = ((size_t)b * N_ + ng * 256 + rr * 16) * (D_ / 4) + dq * 16 + d4;
        float4 acc = make_float4(0.f, 0.f, 0.f, 0.f);
#pragma unroll 16
        for (int i = 0; i < 16; ++i) {
            float4 v = x4[base + (size_t)i * (D_ / 4)];
            acc.x += v.x; acc.y += v.y; acc.z += v.z; acc.w += v.w;
        }
        s4[rr][d4] = acc;
        __syncthreads();
        if (t < 16) {
            float4 a = s4[0][t];
#pragma unroll 15
            for (int r = 1; r < 16; ++r) {
                float4 v = s4[r][t];
                a.x += v.x; a.y += v.y; a.z += v.z; a.w += v.w;
            }
            part4[((size_t)(b * 8 + ng)) * 256 + dq * 16 + t] = a;
        }
    } else {
        orow4[(blk - 512) * 256 + t] = make_float4(0.f, 0.f, 0.f, 0.f);
    }
}

// ---- kB: 128 blocks x 512 thr; block owns h-chunk [h0, h0+8) ----------------
__global__ __launch_bounds__(512) void kB(const float4* __restrict__ part4,
                                          const float* __restrict__ w_qkv,
                                          const float* __restrict__ w_o,
                                          float* __restrict__ orow) {
    const int tid = threadIdx.x;
    const int h0  = blockIdx.x * 8;
    __shared__ float s_xs[4 * 1088];       // padded xsum, 17.4 KB
    __shared__ float s_red[4 * 8 * 64];    // [b][h][dg], 8 KB
    __shared__ float s2[256];              // [b][h][q]
    __shared__ float s_vs[32];             // [b][h]

    // step 1: xsum[b][d] = sum_ng part[b][ng][d]  (128 KB, L2/L3-served)
#pragma unroll
    for (int k = 0; k < 2; ++k) {
        const int task = tid + k * 512;    // (b, d4)
        const int b = task >> 8, d4 = task & 255;
        const float4* p = part4 + (size_t)b * 8 * 256 + d4;
        float4 acc = make_float4(0.f, 0.f, 0.f, 0.f);
#pragma unroll
        for (int g = 0; g < 8; ++g) {
            float4 v = p[(size_t)g * 256];
            acc.x += v.x; acc.y += v.y; acc.z += v.z; acc.w += v.w;
        }
        const int d = d4 * 4;
        XS(b, d + 0) = acc.x;
        XS(b, d + 1) = acc.y;
        XS(b, d + 2) = acc.z;
        XS(b, d + 3) = acc.w;
    }
    __syncthreads();

    // step 2: vs[b][h] = sum_d xsum[b][d] * Wv[d, h0+h];  512 = 64 dg x 8 h
    {
        const int h  = tid & 7;
        const int dg = tid >> 3;
        const float* wv = w_qkv + 2 * H_ + h0 + h;
        float a0 = 0.f, a1 = 0.f, a2 = 0.f, a3 = 0.f;
#pragma unroll 4
        for (int i = 0; i < 16; ++i) {
            const int d = dg * 16 + i;
            const float w = wv[(size_t)d * H3_];
            a0 += XS(0, d) * w;
            a1 += XS(1, d) * w;
            a2 += XS(2, d) * w;
            a3 += XS(3, d) * w;
        }
        s_red[(0 * 8 + h) * 64 + dg] = a0;
        s_red[(1 * 8 + h) * 64 + dg] = a1;
        s_red[(2 * 8 + h) * 64 + dg] = a2;
        s_red[(3 * 8 + h) * 64 + dg] = a3;
    }
    __syncthreads();
    if (tid < 256) {                       // t = b*64 + h*8 + q
        const int q = tid & 7;
        float v = 0.f;
#pragma unroll
        for (int k = 0; k < 8; ++k) v += s_red[(tid >> 3) * 64 + q * 8 + k];
        s2[tid] = v;
    }
    __syncthreads();
    if (tid < 32) {                        // t = b*8 + h
        const int b = tid >> 3, h = tid & 7;
        float v = 0.f;
#pragma unroll
        for (int q = 0; q < 8; ++q) v += s2[b * 64 + h * 8 + q];
        s_vs[b * 8 + h] = v;
    }
    __syncthreads();

    // step 3: orow[b][d] += sum_j vs[b][j] * Wo[h0+j][d]   (coalesced in d)
#pragma unroll
    for (int k = 0; k < 2; ++k) {
        const int d = tid + k * 512;
        float o0 = 0.f, o1 = 0.f, o2 = 0.f, o3 = 0.f;
#pragma unroll
        for (int j = 0; j < 8; ++j) {
            const float w = w_o[(size_t)(h0 + j) * D_ + d];
            o0 += s_vs[ 0 + j] * w;
            o1 += s_vs[ 8 + j] * w;
            o2 += s_vs[16 + j] * w;
            o3 += s_vs[24 + j] * w;
        }
        atomicAdd(&orow[0 * D_ + d], o0);
        atomicAdd(&orow[1 * D_ + d], o1);
        atomicAdd(&orow[2 * D_ + d], o2);
        atomicAdd(&orow[3 * D_ + d], o3);
    }
}

// ---- kC: 512 blocks (b, g): out[b, g*16 .. +16, :] = orow[b, :] ------------
__global__ __launch_bounds__(256) void kC(const float* __restrict__ orow,
                                          float* __restrict__ out) {
    const int blk = blockIdx.x;
    const int b = blk >> 7, g = blk & 127;
    const int t = threadIdx.x;
    const float4 val = reinterpret_cast<const float4*>(orow)[b * 256 + t];
    float4* out4 = reinterpret_cast<float4*>(out);
    size_t base = ((size_t)b * N_ + g * 16) * (D_ / 4) + t;
#pragma unroll 16
    for (int i = 0; i < 16; ++i)
        out4[base + (size_t)i * (D_ / 4)] = val;
}

extern "C" void kernel_launch(void* const* d_in, const int* in_sizes, int n_in,
                              void* d_out, int out_size, void* d_ws, size_t ws_size,
                              hipStream_t stream) {
    const float* x     = (const float*)d_in[0];   // [B, N, D]
    const float* w_qkv = (const float*)d_in[1];   // [D, 3H]
    const float* w_o   = (const float*)d_in[2];   // [H, D]
    // d_in[3] = alpha — provably unused (a == 1 regardless of alpha).
    float* out = (float*)d_out;                   // [B, N, D] fp32

    float* part = (float*)d_ws;                   // 4*8*1024 = 32768 floats (128 KB)
    float* orow = part + (size_t)B_ * 8 * D_;     // 4096 floats

    kA<<<516, 256, 0, stream>>>(x, (float4*)part, (float4*)orow);
    kB<<<128, 512, 0, stream>>>((const float4*)part, w_qkv, w_o, orow);
    kC<<<512, 256, 0, stream>>>(orow, out);
}